// Round 1
// baseline (57.674 us; speedup 1.0000x reference)
//
#include <hip/hip_runtime.h>
#include <hip/hip_bf16.h>

// out[g] = sum over atoms a in graph g of weight[atom_types[a]]
// N_GRAPHS=8192, ATOMS_PER_GRAPH=64 (n_node is constant 64), N_TYPES=118.
// Each lane handles 4 atoms via one int4 load; 16 lanes == one graph;
// shfl_xor reduce within the 16-lane group; one float store per graph.

#define N_TYPES 118

__global__ __launch_bounds__(256) void lre_kernel(
    const int* __restrict__ atom_types,   // (n_atoms,)
    const float* __restrict__ weight,     // (118,)
    float* __restrict__ out,              // (n_graphs,)
    int n_atoms4)                         // n_atoms / 4
{
    __shared__ float w[N_TYPES];
    for (int i = threadIdx.x; i < N_TYPES; i += blockDim.x)
        w[i] = weight[i];
    __syncthreads();

    int tid = blockIdx.x * blockDim.x + threadIdx.x;
    if (tid >= n_atoms4) return;

    const int4 a = ((const int4*)atom_types)[tid];   // 4 atoms, 16B coalesced
    float v = w[a.x] + w[a.y] + w[a.z] + w[a.w];

    // 16 lanes (64 atoms) per graph; xor-reduce stays inside each 16-lane group
    v += __shfl_xor(v, 8, 64);
    v += __shfl_xor(v, 4, 64);
    v += __shfl_xor(v, 2, 64);
    v += __shfl_xor(v, 1, 64);

    if ((tid & 15) == 0)
        out[tid >> 4] = v;
}

extern "C" void kernel_launch(void* const* d_in, const int* in_sizes, int n_in,
                              void* d_out, int out_size, void* d_ws, size_t ws_size,
                              hipStream_t stream) {
    const int* atom_types = (const int*)d_in[0];   // int32 (n_atoms,)
    // d_in[1] = n_node (constant 64 per graph; unused — graph = atom_idx/64)
    const float* weight = (const float*)d_in[2];   // float32 (1,118)
    float* out = (float*)d_out;                    // float32 (n_graphs,1)

    const int n_atoms = in_sizes[0];
    const int n_atoms4 = n_atoms / 4;
    const int block = 256;
    const int grid = (n_atoms4 + block - 1) / block;
    lre_kernel<<<grid, block, 0, stream>>>(atom_types, weight, out, n_atoms4);
}

// Round 2
// 56.930 us; speedup vs baseline: 1.0131x; 1.0131x over previous
//
#include <hip/hip_runtime.h>
#include <hip/hip_bf16.h>

// out[g] = sum over atoms a in graph g of weight[atom_types[a]]
// N_GRAPHS=8192, ATOMS_PER_GRAPH=64 (n_node is constant 64), N_TYPES=118.
// Each thread: 2 int4 loads = 8 atoms; 8 consecutive lanes = 1 graph;
// 3-step shfl_xor reduce inside each aligned 8-lane group; 1 store/graph.

#define N_TYPES 118

__global__ __launch_bounds__(256) void lre_kernel(
    const int4* __restrict__ at4,        // atom_types as int4, n_atoms/4 elems
    const float* __restrict__ weight,    // (118,)
    float* __restrict__ out)             // (n_graphs,)
{
    __shared__ float w[N_TYPES];
    if (threadIdx.x < N_TYPES)
        w[threadIdx.x] = weight[threadIdx.x];
    __syncthreads();

    const int tid = blockIdx.x * 256 + threadIdx.x;   // exact-fit grid, no tail
    const int4 a = at4[2 * tid];
    const int4 b = at4[2 * tid + 1];

    float v = w[a.x] + w[a.y] + w[a.z] + w[a.w]
            + w[b.x] + w[b.y] + w[b.z] + w[b.w];

    // 8 lanes (64 atoms) per graph; xor-reduce stays inside aligned 8-lane groups
    v += __shfl_xor(v, 4, 64);
    v += __shfl_xor(v, 2, 64);
    v += __shfl_xor(v, 1, 64);

    if ((tid & 7) == 0)
        out[tid >> 3] = v;
}

extern "C" void kernel_launch(void* const* d_in, const int* in_sizes, int n_in,
                              void* d_out, int out_size, void* d_ws, size_t ws_size,
                              hipStream_t stream) {
    const int4* at4 = (const int4*)d_in[0];        // int32 atom_types, n_atoms/4 int4s
    // d_in[1] = n_node (constant 64 per graph; graph = atom_idx / 64)
    const float* weight = (const float*)d_in[2];   // float32 (1,118)
    float* out = (float*)d_out;                    // float32 (n_graphs,1)

    const int n_atoms = in_sizes[0];               // 524288
    const int threads_total = n_atoms / 8;         // 65536
    const int block = 256;
    const int grid = threads_total / block;        // 256 blocks
    lre_kernel<<<grid, block, 0, stream>>>(at4, weight, out);
}